// Round 14
// baseline (317.027 us; speedup 1.0000x reference)
//
#include <hip/hip_runtime.h>

#define HA 256
#define WA 256
#define HB 128
#define WB 128
#define PA 48
#define PB 48
#define PP 96
#define MM 32
#define NPIXA (HA*WA)   // 65536
#define NPIXB (HB*WB)   // 16384

typedef short bf16x8 __attribute__((ext_vector_type(8)));
typedef float f32x4 __attribute__((ext_vector_type(4)));

__device__ __forceinline__ float gelu_f(float x) {
    float z = 0.7978845608028654f * (x + 0.044715f * x * x * x);
    float e = __expf(2.0f * z);
    return x - x / (e + 1.0f);
}

__device__ __forceinline__ short f2bf(float f) {
    unsigned u = __float_as_uint(f);
    unsigned r = (u + 0x7FFFu + ((u >> 16) & 1u)) >> 16;
    return (short)r;
}

__device__ __forceinline__ unsigned pack2(float a, float b) {
    return (unsigned)(unsigned short)f2bf(a) | ((unsigned)(unsigned short)f2bf(b) << 16);
}

// ---------------- tables + encoder + weight transforms, fused ----------------
__global__ __launch_bounds__(256) void k_pre(
        float* tiyA, float* tixB, float* tiyB, short* T2x,
        const float* u_a, const float* x_a, const float* u_b, const float* x_b,
        const float* wa, const float* ba, const float* wb, const float* bb,
        float* UA, float* UB,
        const float* c1b_w, const float* c2b_w, short* WT,
        short* TbfA, short* TbfB,
        const float* c1a_w, const float* c2a_w, short* WcT,
        short* Ty2A, short* Ty2B,
        short* TyIA, short* TyIB, short* T2xB) {
    const float TWO_PI = 6.28318530717958647692f;
    int bid = blockIdx.x;
    if (bid < 48) {
        int t = bid * 256 + threadIdx.x;
        if (t < MM * WA) {
            int k = t / WA, x = t - k * WA;
            int m = (k * x) & (WA - 1);
            float ang = TWO_PI * (float)m / (float)WA;
            float s, c; __sincosf(ang, &s, &c);
            float wgt = (k == 0) ? 1.0f : 2.0f;
            T2x[x*64 + 2*k]   = f2bf(wgt * c);
            T2x[x*64 + 2*k+1] = f2bf(-wgt * s);
            int ky = k - 16;
            int my = (ky * x) & (HA - 1);
            float angy = TWO_PI * (float)my / (float)HA;
            float sy, cy; __sincosf(angy, &sy, &cy);
            tiyA[2*t] = cy; tiyA[2*t+1] = sy;
        } else if (t < MM * WA + MM * WB) {
            int t2 = t - MM * WA;
            int k = t2 / WB, x = t2 - k * WB;
            int m = (k * x) & (WB - 1);
            float ang = TWO_PI * (float)m / (float)WB;
            float s, c; __sincosf(ang, &s, &c);
            float wgt = (k == 0) ? 1.0f : 2.0f;
            tixB[2*t2] = wgt * c; tixB[2*t2+1] = wgt * s;
            int ky = k - 16;
            int my = (ky * x) & (HB - 1);
            float angy = TWO_PI * (float)my / (float)HB;
            float sy, cy; __sincosf(angy, &sy, &cy);
            tiyB[2*t2] = cy; tiyB[2*t2+1] = sy;
        }
    } else if (bid < 15408) {
        int eb = bid - 48;
        int o = eb / 320;
        int chunk = eb - o * 320;
        if (chunk < 256) {
            int pix = chunk * 256 + threadIdx.x;
            UA[(size_t)o*NPIXA + pix] = wa[o*3+0]*x_a[pix] + wa[o*3+1]*x_a[NPIXA+pix]
                                      + wa[o*3+2]*u_a[pix] + ba[o];
        } else {
            int pix = (chunk - 256) * 256 + threadIdx.x;
            UB[(size_t)o*NPIXB + pix] = wb[o*3+0]*x_b[pix] + wb[o*3+1]*x_b[NPIXB+pix]
                                      + wb[o*3+2]*u_b[pix] + bb[o];
        }
    } else if (bid < 16272) {
        int g = (bid - 15408) * 256 + threadIdx.x;
        if (g < 4*2*9*48*64) {
            int l  = g / 55296;
            int r1 = g - l*55296;
            int cv = r1 / 27648;
            int r2 = r1 - cv*27648;
            int tap = r2 / 3072;
            int r3 = r2 - tap*3072;
            int oc = r3 >> 6;
            int ic = r3 & 63;
            const float* src = cv ? c2b_w : c1b_w;
            float v = 0.f;
            if (ic < 48) v = src[(((size_t)l*48 + oc)*48 + ic)*9 + tap];
            WT[g] = f2bf(v);
        }
    } else if (bid < 16336) {
        int g = (bid - 16272) * 256 + threadIdx.x;
        int col = g >> 8, x = g & 255;
        int k = col >> 1, comp = col & 1;
        int m = (k * x) & (WA - 1);
        float ang = TWO_PI * (float)m / (float)WA;
        float s, c; __sincosf(ang, &s, &c);
        float sc = 1.0f / (float)(HA * WA);
        TbfA[col*WA + x] = f2bf(comp ? -s * sc : c * sc);
    } else if (bid < 16368) {
        int g = (bid - 16336) * 256 + threadIdx.x;
        int col = g >> 7, x = g & 127;
        int k = col >> 1, comp = col & 1;
        int m = (k * x) & (WB - 1);
        float ang = TWO_PI * (float)m / (float)WB;
        float s, c; __sincosf(ang, &s, &c);
        float sc = 1.0f / (float)(HB * WB);
        TbfB[col*WB + x] = f2bf(comp ? -s * sc : c * sc);
    } else if (bid < 16464) {
        int g = (bid - 16368) * 256 + threadIdx.x;
        int l  = g / 6144;
        int r  = g - l*6144;
        int cv = r / 3072;
        int r2 = r - cv*3072;
        int oc = r2 >> 6;
        int ic = r2 & 63;
        const float* src = cv ? c2a_w : c1a_w;
        float v = 0.f;
        if (ic < 48) v = src[((size_t)l*48 + oc)*48 + ic];
        WcT[g] = f2bf(v);
    } else if (bid < 16592) {
        int g = (bid - 16464) * 256 + threadIdx.x;
        int row = g >> 9, col = g & 511;
        int j = row >> 1, comp = row & 1;
        int y = col >> 1, comp2 = col & 1;
        int my = ((j - 16) * y) & (HA - 1);
        float ang = TWO_PI * (float)my / (float)HA;
        float sy, cy; __sincosf(ang, &sy, &cy);
        float v = comp == 0 ? (comp2 == 0 ? cy : sy) : (comp2 == 0 ? -sy : cy);
        Ty2A[g] = f2bf(v);
    } else if (bid < 16656) {
        int g = (bid - 16592) * 256 + threadIdx.x;
        int row = g >> 8, col = g & 255;
        int j = row >> 1, comp = row & 1;
        int y = col >> 1, comp2 = col & 1;
        int my = ((j - 16) * y) & (HB - 1);
        float ang = TWO_PI * (float)my / (float)HB;
        float sy, cy; __sincosf(ang, &sy, &cy);
        float v = comp == 0 ? (comp2 == 0 ? cy : sy) : (comp2 == 0 ? -sy : cy);
        Ty2B[g] = f2bf(v);
    } else if (bid < 16720) {
        int g = (bid - 16656) * 256 + threadIdx.x;
        int y = g >> 6, col = g & 63;
        int j = col >> 1, comp = col & 1;
        int my = ((j - 16) * y) & (HA - 1);
        float ang = TWO_PI * (float)my / (float)HA;
        float sy, cy; __sincosf(ang, &sy, &cy);
        TyIA[g] = f2bf(comp ? sy : cy);
    } else if (bid < 16752) {
        int g = (bid - 16720) * 256 + threadIdx.x;
        int y = g >> 6, col = g & 63;
        int j = col >> 1, comp = col & 1;
        int my = ((j - 16) * y) & (HB - 1);
        float ang = TWO_PI * (float)my / (float)HB;
        float sy, cy; __sincosf(ang, &sy, &cy);
        TyIB[g] = f2bf(comp ? sy : cy);
    } else {
        int g = (bid - 16752) * 256 + threadIdx.x;
        int x = g >> 6, col = g & 63;
        int k = col >> 1, comp = col & 1;
        int m = (k * x) & (WB - 1);
        float ang = TWO_PI * (float)m / (float)WB;
        float s, c; __sincosf(ang, &s, &c);
        float wgt = (k == 0) ? 1.0f : 2.0f;
        T2xB[g] = f2bf(comp ? -wgt * s : wgt * c);
    }
}

// ---------------- forward DFT along x via MFMA; coalesced FT writes ----------------
__global__ __launch_bounds__(256) void k_fwd_x(
        const float* __restrict__ UA, const float* __restrict__ UB,
        short* __restrict__ FTA, short* __restrict__ FTB,
        const short* __restrict__ TbfA, const short* __restrict__ TbfB) {
    extern __shared__ short lsb[];
    int bid = blockIdx.x;
    const float* U; short* FT; const short* T; int N, ymask, cshift;
    if (bid < 384) { U = UA; FT = FTA; T = TbfA; N = WA; ymask = 255; cshift = 8; }
    else { bid -= 384; U = UB; FT = FTB; T = TbfB; N = WB; ymask = 127; cshift = 7; }
    int r0 = bid * 32;
    int c = r0 >> cshift;
    int ybase = r0 & ymask;
    int NP = N + 8;
    int nq = N >> 2;
    const float4* src = (const float4*)(U + (size_t)r0 * N);
    for (int i = threadIdx.x; i < 32*nq; i += 256) {
        int r = i / nq, q = i - r*nq;
        float4 v = src[i];
        *(uint2*)(lsb + r*NP + q*4) = make_uint2(pack2(v.x, v.y), pack2(v.z, v.w));
    }
    __syncthreads();
    int wv = threadIdx.x >> 6, lane = threadIdx.x & 63;
    int n = lane & 15, kg = lane >> 4;
    int col = wv*16 + n;
    const short* Tc = T + (size_t)col * N;
    f32x4 acc0 = {0.f,0.f,0.f,0.f}, acc1 = {0.f,0.f,0.f,0.f};
    for (int ks = 0; ks < (N >> 5); ++ks) {
        bf16x8 bfrag = *(const bf16x8*)(Tc + ks*32 + kg*8);
        bf16x8 a0 = *(const bf16x8*)(lsb + (size_t)n*NP + ks*32 + kg*8);
        bf16x8 a1 = *(const bf16x8*)(lsb + (size_t)(16+n)*NP + ks*32 + kg*8);
        acc0 = __builtin_amdgcn_mfma_f32_16x16x32_bf16(a0, bfrag, acc0, 0, 0, 0);
        acc1 = __builtin_amdgcn_mfma_f32_16x16x32_bf16(a1, bfrag, acc1, 0, 0, 0);
    }
    __syncthreads();
    short* trb = lsb;
    #pragma unroll
    for (int r = 0; r < 4; ++r) {
        trb[col*36 + kg*4 + r]      = f2bf(acc0[r]);
        trb[col*36 + 16 + kg*4 + r] = f2bf(acc1[r]);
    }
    __syncthreads();
    int K2 = 2 * (ymask + 1);
    for (int idx = threadIdx.x; idx < 512; idx += 256) {
        int kx = idx >> 4, q = idx & 15;
        int yl = q * 2;
        unsigned lo = (unsigned)(unsigned short)trb[(2*kx+0)*36 + yl]
                    | ((unsigned)(unsigned short)trb[(2*kx+1)*36 + yl] << 16);
        unsigned hi = (unsigned)(unsigned short)trb[(2*kx+0)*36 + yl+1]
                    | ((unsigned)(unsigned short)trb[(2*kx+1)*36 + yl+1] << 16);
        *(uint2*)(FT + ((size_t)(c*32 + kx))*K2 + 2*(size_t)ybase + yl*2) = make_uint2(lo, hi);
    }
}

// ---------------- forward DFT along y via MFMA (4-way K-split partials) ----------------
__global__ __launch_bounds__(256) void k_fwd_y(
        const short* __restrict__ FTA, const short* __restrict__ FTB,
        const short* __restrict__ Ty2A, const short* __restrict__ Ty2B,
        float* __restrict__ CIN4) {
    __shared__ short lsb[32*136];
    int bid = blockIdx.x;
    const short* FT; const short* Ty; int K2, NP, pbase, c, h;
    if (bid < 192) { c = bid>>2; h = bid&3; FT = FTA; Ty = Ty2A; K2 = 512; NP = 136; pbase = 0; }
    else { int b2 = bid - 192; c = b2>>2; h = b2&3; FT = FTB; Ty = Ty2B; K2 = 256; NP = 72; pbase = 48; }
    float* CO = CIN4 + (size_t)h * (PP*MM*MM*2);
    int hlen = K2 >> 2;
    int nchunk = hlen >> 3;
    for (int idx = threadIdx.x; idx < 32*nchunk; idx += 256) {
        int row = idx / nchunk, q = idx - row*nchunk;
        *(uint4*)(lsb + row*NP + q*8) =
            *(const uint4*)(FT + ((size_t)c*32 + row)*K2 + h*hlen + q*8);
    }
    __syncthreads();
    int w = threadIdx.x >> 6, lane = threadIdx.x & 63;
    int n = lane & 15, kg = lane >> 4;
    f32x4 acc0 = {0.f,0.f,0.f,0.f}, acc1 = {0.f,0.f,0.f,0.f};
    int nks = hlen >> 5;
    for (int ks = 0; ks < nks; ++ks) {
        bf16x8 af = *(const bf16x8*)(Ty + (size_t)(w*16 + n)*K2 + h*hlen + ks*32 + kg*8);
        bf16x8 b0 = *(const bf16x8*)(lsb + n*NP + ks*32 + kg*8);
        bf16x8 b1 = *(const bf16x8*)(lsb + (16+n)*NP + ks*32 + kg*8);
        acc0 = __builtin_amdgcn_mfma_f32_16x16x32_bf16(af, b0, acc0, 0, 0, 0);
        acc1 = __builtin_amdgcn_mfma_f32_16x16x32_bf16(af, b1, acc1, 0, 0, 0);
    }
    #pragma unroll
    for (int r = 0; r < 4; ++r) {
        int row = w*16 + kg*4 + r;
        int j = row >> 1, comp = row & 1;
        size_t base = (((size_t)(pbase + c))*32 + j)*32;
        CO[(base + n)*2 + comp]      = acc0[r];
        CO[(base + 16 + n)*2 + comp] = acc1[r];
    }
}

// ---------------- collapse 4 CIN partials ----------------
__global__ __launch_bounds__(256) void k_csum(
        const float4* __restrict__ CIN4, float4* __restrict__ CINs) {
    int t = blockIdx.x * 256 + threadIdx.x;    // 49152
    const int S = PP*MM*MM*2/4;                // 49152 float4 per partial
    float4 a = CIN4[t], b = CIN4[t + S], c = CIN4[t + 2*S], d = CIN4[t + 3*S];
    CINs[t] = make_float4(a.x+b.x+c.x+d.x, a.y+b.y+c.y+d.y,
                          a.z+b.z+c.z+d.z, a.w+b.w+c.w+d.w);
}

// ---------------- spectral mix: float4, 8-way q-split, 4 modes/thread ----------------
__global__ __launch_bounds__(256) void k_spectral(
        const float* __restrict__ Wre, const float* __restrict__ Wim,
        const float* __restrict__ CINs, float2* __restrict__ PART) {
    int part = blockIdx.y;
    int t = blockIdx.x * 256 + threadIdx.x;
    int p = t >> 8;
    int m4 = (t & 255) << 2;
    int q0 = part * 12;
    const float4* wr = (const float4*)(Wre + ((size_t)p * PP + q0) * 1024 + m4);
    const float4* wi = (const float4*)(Wim + ((size_t)p * PP + q0) * 1024 + m4);
    const float4* ca = (const float4*)(CINs + (size_t)q0 * 2048 + m4*2);
    float re0=0,re1=0,re2=0,re3=0, im0=0,im1=0,im2=0,im3=0;
    #pragma unroll
    for (int q = 0; q < 12; ++q) {
        float4 a = wr[q * 256];
        float4 b = wi[q * 256];
        float4 c0 = ca[q * 512];
        float4 c1 = ca[q * 512 + 1];
        re0 += a.x*c0.x - b.x*c0.y;  im0 += a.x*c0.y + b.x*c0.x;
        re1 += a.y*c0.z - b.y*c0.w;  im1 += a.y*c0.w + b.y*c0.z;
        re2 += a.z*c1.x - b.z*c1.y;  im2 += a.z*c1.y + b.z*c1.x;
        re3 += a.w*c1.z - b.w*c1.w;  im3 += a.w*c1.w + b.w*c1.z;
    }
    float2* po = PART + ((size_t)part * PP + p) * 1024 + m4;
    po[0] = make_float2(re0, im0);
    po[1] = make_float2(re1, im1);
    po[2] = make_float2(re2, im2);
    po[3] = make_float2(re3, im3);
}

// ---------------- inverse DFT along y via MFMA (fuses 8-partial sum) ----------------
// A: bid<192 (c, y-quarter); B: 192..287 (c, y-half).
__global__ __launch_bounds__(256) void k_invy(
        const float2* __restrict__ PART,
        const short* __restrict__ TyIA, const short* __restrict__ TyIB,
        short* __restrict__ DA, short* __restrict__ DB) {
    __shared__ short A2[64*72];
    int bid = blockIdx.x;
    int c, ybase, cb; const short* Ty; short* D;
    if (bid < 192) { c = bid >> 2; ybase = (bid & 3) * 64; Ty = TyIA; D = DA; cb = c; }
    else { int b2 = bid - 192; c = 48 + (b2 >> 1); ybase = (b2 & 1) * 64; Ty = TyIB; D = DB; cb = c - 48; }
    for (int idx = threadIdx.x; idx < 1024; idx += 256) {
        int j = idx >> 5, kx = idx & 31;
        float re = 0.f, im = 0.f;
        const float2* pp = PART + (size_t)c*1024 + idx;
        #pragma unroll
        for (int u = 0; u < 8; ++u) {
            float2 v = pp[(size_t)u*PP*1024];
            re += v.x; im += v.y;
        }
        A2[(2*kx+0)*72 + 2*j]   = f2bf(re);
        A2[(2*kx+0)*72 + 2*j+1] = f2bf(-im);
        A2[(2*kx+1)*72 + 2*j]   = f2bf(im);
        A2[(2*kx+1)*72 + 2*j+1] = f2bf(re);
    }
    __syncthreads();
    int wv = threadIdx.x >> 6, lane = threadIdx.x & 63;
    int n = lane & 15, kg = lane >> 4;
    int y = ybase + wv*16 + n;
    bf16x8 bf0 = *(const bf16x8*)(Ty + (size_t)y*64 + kg*8);
    bf16x8 bf1 = *(const bf16x8*)(Ty + (size_t)y*64 + 32 + kg*8);
    #pragma unroll
    for (int mt = 0; mt < 4; ++mt) {
        bf16x8 a0 = *(const bf16x8*)(A2 + (mt*16 + n)*72 + kg*8);
        bf16x8 a1 = *(const bf16x8*)(A2 + (mt*16 + n)*72 + 32 + kg*8);
        f32x4 acc = {0.f,0.f,0.f,0.f};
        acc = __builtin_amdgcn_mfma_f32_16x16x32_bf16(a0, bf0, acc, 0, 0, 0);
        acc = __builtin_amdgcn_mfma_f32_16x16x32_bf16(a1, bf1, acc, 0, 0, 0);
        int row0 = mt*16 + kg*4;
        *(uint2*)(D + (size_t)y*3072 + cb*64 + row0) =
            make_uint2(pack2(acc[0], acc[1]), pack2(acc[2], acc[3]));
    }
}

// ---------------- fused inverse tail ----------------
__global__ __launch_bounds__(256) void k_inv(
        const short* __restrict__ DA, const short* __restrict__ DB,
        float* __restrict__ UA, short* __restrict__ SBbf,
        const short* __restrict__ T2x, const short* __restrict__ T2xB,
        const short* __restrict__ W1T, const short* __restrict__ W2T,
        const float* __restrict__ b1v, const float* __restrict__ b2v) {
    __shared__ __attribute__((aligned(16))) char smc[37888];
    int t = threadIdx.x;
    int wv = t >> 6, lane = t & 63;
    int n = lane & 15, kg = lane >> 4;
    if (blockIdx.x < 512) {
        short* b0bf  = (short*)smc;                  // [128][72]
        short* slbf  = (short*)(smc + 18432);        // [128][72]
        float* bl1   = (float*)(smc + 37120);
        float* bl2   = (float*)(smc + 37312);
        int y  = blockIdx.x >> 1;
        int xh = (blockIdx.x & 1) << 7;
        if (t >= 64 && t < 112) bl1[t-64] = b1v[t-64];
        if (t >= 128 && t < 176) bl2[t-128] = b2v[t-128];
        const short* DAy = DA + (size_t)y*3072;
        {
            f32x4 acc[2][3];
            #pragma unroll
            for (int i = 0; i < 2; ++i)
                #pragma unroll
                for (int mt = 0; mt < 3; ++mt)
                    acc[i][mt] = (f32x4){0.f,0.f,0.f,0.f};
            #pragma unroll
            for (int ks = 0; ks < 2; ++ks) {
                bf16x8 bfr[2];
                #pragma unroll
                for (int i = 0; i < 2; ++i) {
                    int px = xh + (wv*2 + i)*16 + n;
                    bfr[i] = *(const bf16x8*)(T2x + (size_t)px*64 + ks*32 + kg*8);
                }
                #pragma unroll
                for (int mt = 0; mt < 3; ++mt) {
                    bf16x8 af = *(const bf16x8*)(DAy + (mt*16 + n)*64 + ks*32 + kg*8);
                    #pragma unroll
                    for (int i = 0; i < 2; ++i)
                        acc[i][mt] = __builtin_amdgcn_mfma_f32_16x16x32_bf16(af, bfr[i], acc[i][mt], 0, 0, 0);
                }
            }
            #pragma unroll
            for (int i = 0; i < 2; ++i) {
                int xl = (wv*2 + i)*16 + n;
                #pragma unroll
                for (int mt = 0; mt < 3; ++mt)
                    #pragma unroll
                    for (int r = 0; r < 4; ++r)
                        slbf[xl*72 + mt*16 + kg*4 + r] = f2bf(acc[i][mt][r]);
            }
            for (int idx = t; idx < 2048; idx += 256)
                slbf[(idx >> 4)*72 + 48 + (idx & 15)] = 0;
        }
        __syncthreads();
        {
            bf16x8 aw[3][2];
            #pragma unroll
            for (int mt = 0; mt < 3; ++mt)
                #pragma unroll
                for (int ks = 0; ks < 2; ++ks)
                    aw[mt][ks] = *(const bf16x8*)(W1T + (size_t)(mt*16 + n)*64 + ks*32 + kg*8);
            f32x4 acc[2][3];
            #pragma unroll
            for (int nt = 0; nt < 2; ++nt)
                #pragma unroll
                for (int mt = 0; mt < 3; ++mt)
                    acc[nt][mt] = (f32x4){0.f,0.f,0.f,0.f};
            #pragma unroll
            for (int nt = 0; nt < 2; ++nt) {
                int ntile = wv*2 + nt;
                #pragma unroll
                for (int ks = 0; ks < 2; ++ks) {
                    bf16x8 bfrag = *(const bf16x8*)(slbf + (size_t)(ntile*16 + n)*72 + ks*32 + kg*8);
                    #pragma unroll
                    for (int mt = 0; mt < 3; ++mt)
                        acc[nt][mt] = __builtin_amdgcn_mfma_f32_16x16x32_bf16(aw[mt][ks], bfrag, acc[nt][mt], 0, 0, 0);
                }
            }
            #pragma unroll
            for (int nt = 0; nt < 2; ++nt) {
                int px = (wv*2 + nt)*16 + n;
                #pragma unroll
                for (int mt = 0; mt < 3; ++mt) {
                    int oc0 = mt*16 + kg*4;
                    float g0 = gelu_f(acc[nt][mt][0] + bl1[oc0+0]);
                    float g1 = gelu_f(acc[nt][mt][1] + bl1[oc0+1]);
                    float g2 = gelu_f(acc[nt][mt][2] + bl1[oc0+2]);
                    float g3 = gelu_f(acc[nt][mt][3] + bl1[oc0+3]);
                    *(uint2*)(b0bf + (size_t)px*72 + oc0) = make_uint2(pack2(g0,g1), pack2(g2,g3));
                }
            }
            for (int idx = t; idx < 2048; idx += 256)
                b0bf[(idx >> 4)*72 + 48 + (idx & 15)] = 0;
        }
        __syncthreads();
        {
            bf16x8 aw[3][2];
            #pragma unroll
            for (int mt = 0; mt < 3; ++mt)
                #pragma unroll
                for (int ks = 0; ks < 2; ++ks)
                    aw[mt][ks] = *(const bf16x8*)(W2T + (size_t)(mt*16 + n)*64 + ks*32 + kg*8);
            f32x4 acc[2][3];
            #pragma unroll
            for (int nt = 0; nt < 2; ++nt)
                #pragma unroll
                for (int mt = 0; mt < 3; ++mt)
                    acc[nt][mt] = (f32x4){0.f,0.f,0.f,0.f};
            #pragma unroll
            for (int nt = 0; nt < 2; ++nt) {
                int ntile = wv*2 + nt;
                #pragma unroll
                for (int ks = 0; ks < 2; ++ks) {
                    bf16x8 bfrag = *(const bf16x8*)(b0bf + (size_t)(ntile*16 + n)*72 + ks*32 + kg*8);
                    #pragma unroll
                    for (int mt = 0; mt < 3; ++mt)
                        acc[nt][mt] = __builtin_amdgcn_mfma_f32_16x16x32_bf16(aw[mt][ks], bfrag, acc[nt][mt], 0, 0, 0);
                }
            }
            #pragma unroll
            for (int nt = 0; nt < 2; ++nt) {
                int px = (wv*2 + nt)*16 + n;
                #pragma unroll
                for (int mt = 0; mt < 3; ++mt) {
                    int oc0 = mt*16 + kg*4;
                    #pragma unroll
                    for (int r = 0; r < 4; ++r) {
                        int oc = oc0 + r;
                        size_t o = (size_t)oc*NPIXA + (size_t)y*WA + xh + px;
                        UA[o] = gelu_f(acc[nt][mt][r] + bl2[oc]) + UA[o];
                    }
                }
            }
        }
    } else {
        int y = blockIdx.x - 512;
        short* sbuf = (short*)smc;    // [48][132]
        const short* DBy = DB + (size_t)y*3072;
        #pragma unroll
        for (int ntl = 0; ntl < 2; ++ntl) {
            int nt = wv*2 + ntl;
            int x = nt*16 + n;
            bf16x8 bf0 = *(const bf16x8*)(T2xB + (size_t)x*64 + kg*8);
            bf16x8 bf1 = *(const bf16x8*)(T2xB + (size_t)x*64 + 32 + kg*8);
            #pragma unroll
            for (int mt = 0; mt < 3; ++mt) {
                bf16x8 a0 = *(const bf16x8*)(DBy + (mt*16 + n)*64 + kg*8);
                bf16x8 a1 = *(const bf16x8*)(DBy + (mt*16 + n)*64 + 32 + kg*8);
                f32x4 acc = {0.f,0.f,0.f,0.f};
                acc = __builtin_amdgcn_mfma_f32_16x16x32_bf16(a0, bf0, acc, 0, 0, 0);
                acc = __builtin_amdgcn_mfma_f32_16x16x32_bf16(a1, bf1, acc, 0, 0, 0);
                int c0 = mt*16 + kg*4;
                #pragma unroll
                for (int r = 0; r < 4; ++r)
                    sbuf[(c0 + r)*132 + x] = f2bf(acc[r]);
            }
        }
        __syncthreads();
        for (int idx = t; idx < 3072; idx += 256) {
            int x = idx / 24, cu = idx - x*24;
            unsigned v = (unsigned)(unsigned short)sbuf[(2*cu)*132 + x]
                       | ((unsigned)(unsigned short)sbuf[(2*cu+1)*132 + x] << 16);
            *(unsigned*)(SBbf + ((size_t)y*WB + x)*48 + 2*cu) = v;
        }
    }
}

// ---------------- B-branch 3x3 conv via MFMA, pixel-major bf16 I/O ----------------
// block = 192 threads (3 waves = 3 mt), 1 row x 16 px x 48 oc. grid 1024.
__global__ __launch_bounds__(192) void k_conv3x3_mfma(
        const short* __restrict__ in, float* __restrict__ outf,
        short* __restrict__ outbf,
        const short* __restrict__ wt, const float* __restrict__ bias,
        const float* resid) {
    __shared__ __attribute__((aligned(16))) short tile[3*18*72];   // 7776 B
    int y  = blockIdx.x >> 3;
    int x0 = (blockIdx.x & 7) << 4;
    int tid = threadIdx.x;
    for (int idx = tid; idx < 54*6; idx += 192) {
        int pix = idx / 6, chunk = idx - pix*6;
        int r = pix / 18, px = pix - r*18;
        int gy = y - 1 + r, gx = x0 - 1 + px;
        uint4 v = {0u,0u,0u,0u};
        if (gy >= 0 && gy < HB && gx >= 0 && gx < WB)
            v = *(const uint4*)(in + ((size_t)gy*WB + gx)*48 + chunk*8);
        *(uint4*)(tile + pix*72 + chunk*8) = v;
    }
    for (int idx = tid; idx < 54*2; idx += 192) {
        int pix = idx >> 1, h = idx & 1;
        *(uint4*)(tile + pix*72 + 48 + h*8) = (uint4){0u,0u,0u,0u};
    }
    __syncthreads();

    int mt = tid / 64, lane = tid & 63;
    int n = lane & 15, kg = lane >> 4;
    f32x4 acc = {0.f,0.f,0.f,0.f};
    #pragma unroll
    for (int tap = 0; tap < 9; ++tap) {
        int dy = tap / 3, dx = tap - dy*3;
        const short* brow = tile + (dy*18 + n + dx)*72;
        const short* ap = wt + (size_t)tap*3072 + (size_t)(mt*16 + n)*64;
        #pragma unroll
        for (int ks = 0; ks < 2; ++ks) {
            bf16x8 bfrag = *(const bf16x8*)(brow + ks*32 + kg*8);
            bf16x8 afrag = *(const bf16x8*)(ap + ks*32 + kg*8);
            acc = __builtin_amdgcn_mfma_f32_16x16x32_bf16(afrag, bfrag, acc, 0, 0, 0);
        }
    }
    int px_g = x0 + n;
    int oc0 = mt*16 + kg*4;
    float g0 = gelu_f(acc[0] + bias[oc0+0]);
    float g1 = gelu_f(acc[1] + bias[oc0+1]);
    float g2 = gelu_f(acc[2] + bias[oc0+2]);
    float g3 = gelu_f(acc[3] + bias[oc0+3]);
    if (outbf) {
        *(uint2*)(outbf + ((size_t)y*WB + px_g)*48 + oc0) =
            make_uint2(pack2(g0, g1), pack2(g2, g3));
    } else {
        float gv[4] = {g0, g1, g2, g3};
        #pragma unroll
        for (int r = 0; r < 4; ++r) {
            size_t o = (size_t)(oc0 + r)*NPIXB + (size_t)y*WB + px_g;
            outf[o] = gv[r] + resid[o];
        }
    }
}

// ---------------- decoder ----------------
__global__ __launch_bounds__(256) void k_decode(
        const float* __restrict__ UA, const float* __restrict__ UB,
        const float* dwa, const float* dba,
        const float* dwb, const float* dbb, float* outp) {
    int t = blockIdx.x*256 + threadIdx.x;
    if (t < NPIXA) {
        float acc = dba[0];
        #pragma unroll 8
        for (int p = 0; p < PA; ++p) acc += dwa[p]*UA[(size_t)p*NPIXA + t];
        outp[t] = acc;
    } else {
        int u = t - NPIXA;
        float acc = dbb[0];
        #pragma unroll 8
        for (int p = 0; p < PB; ++p) acc += dwb[p]*UB[(size_t)p*NPIXB + u];
        outp[t] = acc;
    }
}

extern "C" void kernel_launch(void* const* d_in, const int* in_sizes, int n_in,
                              void* d_out, int out_size, void* d_ws, size_t ws_size,
                              hipStream_t stream) {
    const float* u_a   = (const float*)d_in[0];
    const float* x_a   = (const float*)d_in[1];
    const float* u_b   = (const float*)d_in[2];
    const float* x_b   = (const float*)d_in[3];
    const float* enc_a_w = (const float*)d_in[4];
    const float* enc_a_b = (const float*)d_in[5];
    const float* enc_b_w = (const float*)d_in[6];
    const float* enc_b_b = (const float*)d_in[7];
    const float* dec_a_w = (const float*)d_in[8];
    const float* dec_a_b = (const float*)d_in[9];
    const float* dec_b_w = (const float*)d_in[10];
    const float* dec_b_b = (const float*)d_in[11];
    const float* c1a_w = (const float*)d_in[12];
    const float* c1a_b = (const float*)d_in[13];
    const float* c2a_w = (const float*)d_in[14];
    const float* c2a_b = (const float*)d_in[15];
    const float* c1b_w = (const float*)d_in[16];
    const float* c1b_b = (const float*)d_in[17];
    const float* c2b_w = (const float*)d_in[18];
    const float* c2b_b = (const float*)d_in[19];
    const float* A_re = (const float*)d_in[20];
    const float* A_im = (const float*)d_in[21];

    float* ws = (float*)d_ws;
    size_t off = 0;
    auto alloc = [&](size_t n) { float* p = ws + off; off += n; return p; };
    short* WT    = (short*)alloc(4*2*9*48*64/2);
    short* TbfA  = (short*)alloc(64*WA/2);
    short* TbfB  = (short*)alloc(64*WB/2);
    short* WcT   = (short*)alloc(4*2*48*64/2);
    short* T2x   = (short*)alloc(WA*64/2);
    short* T2xB  = (short*)alloc(WB*64/2);
    short* Ty2A  = (short*)alloc(64*512/2);
    short* Ty2B  = (short*)alloc(64*256/2);
    short* TyIA  = (short*)alloc(HA*64/2);
    short* TyIB  = (short*)alloc(HB*64/2);
    float* TiyA  = alloc(MM*HA*2);
    float* TixB  = alloc(MM*WB*2);
    float* TiyB  = alloc(MM*HB*2);
    float* UA = alloc((size_t)PA*NPIXA);
    float* UB = alloc((size_t)PB*NPIXB);
    short* SBbf = (short*)alloc((size_t)PB*NPIXB/2);
    short* TBbf = (short*)alloc((size_t)PB*NPIXB/2);
    short* FTA = (short*)alloc((size_t)PA*MM*512/2);
    short* FTB = (short*)alloc((size_t)PB*MM*256/2);
    short* DA  = (short*)alloc((size_t)HA*3072/2);
    short* DB  = (short*)alloc((size_t)HB*3072/2);
    float* CIN4 = alloc((size_t)4*PP*MM*MM*2);
    float* CINs = alloc((size_t)PP*MM*MM*2);
    float2* PART = (float2*)alloc((size_t)8*PP*MM*MM*2);
    if (off * sizeof(float) > ws_size) return;

    k_pre<<<dim3(16784), dim3(256), 0, stream>>>(
        TiyA, TixB, TiyB, T2x,
        u_a,x_a,u_b,x_b, enc_a_w,enc_a_b,enc_b_w,enc_b_b, UA,UB,
        c1b_w, c2b_w, WT, TbfA, TbfB, c1a_w, c2a_w, WcT, Ty2A, Ty2B,
        TyIA, TyIB, T2xB);
    for (int l = 0; l < 4; ++l) {
        k_fwd_x<<<dim3(576), dim3(256), 32*(WA+8)*2, stream>>>(UA,UB,FTA,FTB,TbfA,TbfB);
        k_fwd_y<<<dim3(384), dim3(256), 0, stream>>>(FTA,FTB,Ty2A,Ty2B,CIN4);
        k_csum<<<dim3(192), dim3(256), 0, stream>>>((const float4*)CIN4, (float4*)CINs);
        k_spectral<<<dim3(96,8), dim3(256), 0, stream>>>(
            A_re + (size_t)l*PP*PP*MM*MM, A_im + (size_t)l*PP*PP*MM*MM,
            CINs, PART);
        k_invy<<<dim3(288), dim3(256), 0, stream>>>(PART, TyIA, TyIB, DA, DB);
        k_inv<<<dim3(512 + 128), dim3(256), 0, stream>>>(DA, DB, UA, SBbf,
            T2x, T2xB,
            WcT + (size_t)(l*2 + 0)*3072, WcT + (size_t)(l*2 + 1)*3072,
            c1a_b + (size_t)l*PA, c2a_b + (size_t)l*PA);
        k_conv3x3_mfma<<<dim3(1024), dim3(192), 0, stream>>>(SBbf, (float*)nullptr, TBbf,
            WT + (size_t)(l*2 + 0)*27648, c1b_b + (size_t)l*PB, (const float*)nullptr);
        k_conv3x3_mfma<<<dim3(1024), dim3(192), 0, stream>>>(TBbf, UB, (short*)nullptr,
            WT + (size_t)(l*2 + 1)*27648, c2b_b + (size_t)l*PB, UB);
    }
    k_decode<<<dim3(320), dim3(256), 0, stream>>>(UA, UB,
        dec_a_w, dec_a_b, dec_b_w, dec_b_b, (float*)d_out);
}

// Round 15
// 307.769 us; speedup vs baseline: 1.0301x; 1.0301x over previous
//
#include <hip/hip_runtime.h>

#define HA 256
#define WA 256
#define HB 128
#define WB 128
#define PA 48
#define PB 48
#define PP 96
#define MM 32
#define NPIXA (HA*WA)   // 65536
#define NPIXB (HB*WB)   // 16384

typedef short bf16x8 __attribute__((ext_vector_type(8)));
typedef float f32x4 __attribute__((ext_vector_type(4)));

__device__ __forceinline__ float gelu_f(float x) {
    float z = 0.7978845608028654f * (x + 0.044715f * x * x * x);
    float e = __expf(2.0f * z);
    return x - x / (e + 1.0f);
}

__device__ __forceinline__ short f2bf(float f) {
    unsigned u = __float_as_uint(f);
    unsigned r = (u + 0x7FFFu + ((u >> 16) & 1u)) >> 16;
    return (short)r;
}

__device__ __forceinline__ unsigned pack2(float a, float b) {
    return (unsigned)(unsigned short)f2bf(a) | ((unsigned)(unsigned short)f2bf(b) << 16);
}

// ---------------- tables + encoder + weight transforms, fused ----------------
__global__ __launch_bounds__(256) void k_pre(
        float* tiyA, float* tixB, float* tiyB, short* T2x,
        const float* u_a, const float* x_a, const float* u_b, const float* x_b,
        const float* wa, const float* ba, const float* wb, const float* bb,
        float* UA, float* UB,
        const float* c1b_w, const float* c2b_w, short* WT,
        short* TbfA, short* TbfB,
        const float* c1a_w, const float* c2a_w, short* WcT,
        short* Ty2A, short* Ty2B,
        short* TyIA, short* TyIB, short* T2xB) {
    const float TWO_PI = 6.28318530717958647692f;
    int bid = blockIdx.x;
    if (bid < 48) {
        int t = bid * 256 + threadIdx.x;
        if (t < MM * WA) {
            int k = t / WA, x = t - k * WA;
            int m = (k * x) & (WA - 1);
            float ang = TWO_PI * (float)m / (float)WA;
            float s, c; __sincosf(ang, &s, &c);
            float wgt = (k == 0) ? 1.0f : 2.0f;
            T2x[x*64 + 2*k]   = f2bf(wgt * c);
            T2x[x*64 + 2*k+1] = f2bf(-wgt * s);
            int ky = k - 16;
            int my = (ky * x) & (HA - 1);
            float angy = TWO_PI * (float)my / (float)HA;
            float sy, cy; __sincosf(angy, &sy, &cy);
            tiyA[2*t] = cy; tiyA[2*t+1] = sy;
        } else if (t < MM * WA + MM * WB) {
            int t2 = t - MM * WA;
            int k = t2 / WB, x = t2 - k * WB;
            int m = (k * x) & (WB - 1);
            float ang = TWO_PI * (float)m / (float)WB;
            float s, c; __sincosf(ang, &s, &c);
            float wgt = (k == 0) ? 1.0f : 2.0f;
            tixB[2*t2] = wgt * c; tixB[2*t2+1] = wgt * s;
            int ky = k - 16;
            int my = (ky * x) & (HB - 1);
            float angy = TWO_PI * (float)my / (float)HB;
            float sy, cy; __sincosf(angy, &sy, &cy);
            tiyB[2*t2] = cy; tiyB[2*t2+1] = sy;
        }
    } else if (bid < 15408) {
        int eb = bid - 48;
        int o = eb / 320;
        int chunk = eb - o * 320;
        if (chunk < 256) {
            int pix = chunk * 256 + threadIdx.x;
            UA[(size_t)o*NPIXA + pix] = wa[o*3+0]*x_a[pix] + wa[o*3+1]*x_a[NPIXA+pix]
                                      + wa[o*3+2]*u_a[pix] + ba[o];
        } else {
            int pix = (chunk - 256) * 256 + threadIdx.x;
            UB[(size_t)o*NPIXB + pix] = wb[o*3+0]*x_b[pix] + wb[o*3+1]*x_b[NPIXB+pix]
                                      + wb[o*3+2]*u_b[pix] + bb[o];
        }
    } else if (bid < 16272) {
        int g = (bid - 15408) * 256 + threadIdx.x;
        if (g < 4*2*9*48*64) {
            int l  = g / 55296;
            int r1 = g - l*55296;
            int cv = r1 / 27648;
            int r2 = r1 - cv*27648;
            int tap = r2 / 3072;
            int r3 = r2 - tap*3072;
            int oc = r3 >> 6;
            int ic = r3 & 63;
            const float* src = cv ? c2b_w : c1b_w;
            float v = 0.f;
            if (ic < 48) v = src[(((size_t)l*48 + oc)*48 + ic)*9 + tap];
            WT[g] = f2bf(v);
        }
    } else if (bid < 16336) {
        int g = (bid - 16272) * 256 + threadIdx.x;
        int col = g >> 8, x = g & 255;
        int k = col >> 1, comp = col & 1;
        int m = (k * x) & (WA - 1);
        float ang = TWO_PI * (float)m / (float)WA;
        float s, c; __sincosf(ang, &s, &c);
        float sc = 1.0f / (float)(HA * WA);
        TbfA[col*WA + x] = f2bf(comp ? -s * sc : c * sc);
    } else if (bid < 16368) {
        int g = (bid - 16336) * 256 + threadIdx.x;
        int col = g >> 7, x = g & 127;
        int k = col >> 1, comp = col & 1;
        int m = (k * x) & (WB - 1);
        float ang = TWO_PI * (float)m / (float)WB;
        float s, c; __sincosf(ang, &s, &c);
        float sc = 1.0f / (float)(HB * WB);
        TbfB[col*WB + x] = f2bf(comp ? -s * sc : c * sc);
    } else if (bid < 16464) {
        int g = (bid - 16368) * 256 + threadIdx.x;
        int l  = g / 6144;
        int r  = g - l*6144;
        int cv = r / 3072;
        int r2 = r - cv*3072;
        int oc = r2 >> 6;
        int ic = r2 & 63;
        const float* src = cv ? c2a_w : c1a_w;
        float v = 0.f;
        if (ic < 48) v = src[((size_t)l*48 + oc)*48 + ic];
        WcT[g] = f2bf(v);
    } else if (bid < 16592) {
        int g = (bid - 16464) * 256 + threadIdx.x;
        int row = g >> 9, col = g & 511;
        int j = row >> 1, comp = row & 1;
        int y = col >> 1, comp2 = col & 1;
        int my = ((j - 16) * y) & (HA - 1);
        float ang = TWO_PI * (float)my / (float)HA;
        float sy, cy; __sincosf(ang, &sy, &cy);
        float v = comp == 0 ? (comp2 == 0 ? cy : sy) : (comp2 == 0 ? -sy : cy);
        Ty2A[g] = f2bf(v);
    } else if (bid < 16656) {
        int g = (bid - 16592) * 256 + threadIdx.x;
        int row = g >> 8, col = g & 255;
        int j = row >> 1, comp = row & 1;
        int y = col >> 1, comp2 = col & 1;
        int my = ((j - 16) * y) & (HB - 1);
        float ang = TWO_PI * (float)my / (float)HB;
        float sy, cy; __sincosf(ang, &sy, &cy);
        float v = comp == 0 ? (comp2 == 0 ? cy : sy) : (comp2 == 0 ? -sy : cy);
        Ty2B[g] = f2bf(v);
    } else if (bid < 16720) {
        int g = (bid - 16656) * 256 + threadIdx.x;
        int y = g >> 6, col = g & 63;
        int j = col >> 1, comp = col & 1;
        int my = ((j - 16) * y) & (HA - 1);
        float ang = TWO_PI * (float)my / (float)HA;
        float sy, cy; __sincosf(ang, &sy, &cy);
        TyIA[g] = f2bf(comp ? sy : cy);
    } else if (bid < 16752) {
        int g = (bid - 16720) * 256 + threadIdx.x;
        int y = g >> 6, col = g & 63;
        int j = col >> 1, comp = col & 1;
        int my = ((j - 16) * y) & (HB - 1);
        float ang = TWO_PI * (float)my / (float)HB;
        float sy, cy; __sincosf(ang, &sy, &cy);
        TyIB[g] = f2bf(comp ? sy : cy);
    } else {
        int g = (bid - 16752) * 256 + threadIdx.x;
        int x = g >> 6, col = g & 63;
        int k = col >> 1, comp = col & 1;
        int m = (k * x) & (WB - 1);
        float ang = TWO_PI * (float)m / (float)WB;
        float s, c; __sincosf(ang, &s, &c);
        float wgt = (k == 0) ? 1.0f : 2.0f;
        T2xB[g] = f2bf(comp ? -wgt * s : wgt * c);
    }
}

// ---------------- forward DFT along x via MFMA; coalesced FT writes ----------------
__global__ __launch_bounds__(256) void k_fwd_x(
        const float* __restrict__ UA, const float* __restrict__ UB,
        short* __restrict__ FTA, short* __restrict__ FTB,
        const short* __restrict__ TbfA, const short* __restrict__ TbfB) {
    extern __shared__ short lsb[];
    int bid = blockIdx.x;
    const float* U; short* FT; const short* T; int N, ymask, cshift;
    if (bid < 384) { U = UA; FT = FTA; T = TbfA; N = WA; ymask = 255; cshift = 8; }
    else { bid -= 384; U = UB; FT = FTB; T = TbfB; N = WB; ymask = 127; cshift = 7; }
    int r0 = bid * 32;
    int c = r0 >> cshift;
    int ybase = r0 & ymask;
    int NP = N + 8;
    int nq = N >> 2;
    const float4* src = (const float4*)(U + (size_t)r0 * N);
    for (int i = threadIdx.x; i < 32*nq; i += 256) {
        int r = i / nq, q = i - r*nq;
        float4 v = src[i];
        *(uint2*)(lsb + r*NP + q*4) = make_uint2(pack2(v.x, v.y), pack2(v.z, v.w));
    }
    __syncthreads();
    int wv = threadIdx.x >> 6, lane = threadIdx.x & 63;
    int n = lane & 15, kg = lane >> 4;
    int col = wv*16 + n;
    const short* Tc = T + (size_t)col * N;
    f32x4 acc0 = {0.f,0.f,0.f,0.f}, acc1 = {0.f,0.f,0.f,0.f};
    for (int ks = 0; ks < (N >> 5); ++ks) {
        bf16x8 bfrag = *(const bf16x8*)(Tc + ks*32 + kg*8);
        bf16x8 a0 = *(const bf16x8*)(lsb + (size_t)n*NP + ks*32 + kg*8);
        bf16x8 a1 = *(const bf16x8*)(lsb + (size_t)(16+n)*NP + ks*32 + kg*8);
        acc0 = __builtin_amdgcn_mfma_f32_16x16x32_bf16(a0, bfrag, acc0, 0, 0, 0);
        acc1 = __builtin_amdgcn_mfma_f32_16x16x32_bf16(a1, bfrag, acc1, 0, 0, 0);
    }
    __syncthreads();
    short* trb = lsb;
    #pragma unroll
    for (int r = 0; r < 4; ++r) {
        trb[col*36 + kg*4 + r]      = f2bf(acc0[r]);
        trb[col*36 + 16 + kg*4 + r] = f2bf(acc1[r]);
    }
    __syncthreads();
    int K2 = 2 * (ymask + 1);
    for (int idx = threadIdx.x; idx < 512; idx += 256) {
        int kx = idx >> 4, q = idx & 15;
        int yl = q * 2;
        unsigned lo = (unsigned)(unsigned short)trb[(2*kx+0)*36 + yl]
                    | ((unsigned)(unsigned short)trb[(2*kx+1)*36 + yl] << 16);
        unsigned hi = (unsigned)(unsigned short)trb[(2*kx+0)*36 + yl+1]
                    | ((unsigned)(unsigned short)trb[(2*kx+1)*36 + yl+1] << 16);
        *(uint2*)(FT + ((size_t)(c*32 + kx))*K2 + 2*(size_t)ybase + yl*2) = make_uint2(lo, hi);
    }
}

// ---------------- forward DFT along y via MFMA (2-way K-split partials) ----------------
__global__ __launch_bounds__(256) void k_fwd_y(
        const short* __restrict__ FTA, const short* __restrict__ FTB,
        const short* __restrict__ Ty2A, const short* __restrict__ Ty2B,
        float* __restrict__ CINa, float* __restrict__ CINb) {
    __shared__ short lsb[32*264];
    int bid = blockIdx.x;
    const short* FT; const short* Ty; int K2, NP, pbase, c, h;
    if (bid < 96) { c = bid>>1; h = bid&1; FT = FTA; Ty = Ty2A; K2 = 512; NP = 264; pbase = 0; }
    else { int b2 = bid - 96; c = b2>>1; h = b2&1; FT = FTB; Ty = Ty2B; K2 = 256; NP = 136; pbase = 48; }
    float* CO = (h == 0) ? CINa : CINb;
    int hlen = K2 >> 1;
    int nchunk = hlen >> 3;
    for (int idx = threadIdx.x; idx < 32*nchunk; idx += 256) {
        int row = idx / nchunk, q = idx - row*nchunk;
        *(uint4*)(lsb + row*NP + q*8) =
            *(const uint4*)(FT + ((size_t)c*32 + row)*K2 + h*hlen + q*8);
    }
    __syncthreads();
    int w = threadIdx.x >> 6, lane = threadIdx.x & 63;
    int n = lane & 15, kg = lane >> 4;
    f32x4 acc0 = {0.f,0.f,0.f,0.f}, acc1 = {0.f,0.f,0.f,0.f};
    int nks = hlen >> 5;
    for (int ks = 0; ks < nks; ++ks) {
        bf16x8 af = *(const bf16x8*)(Ty + (size_t)(w*16 + n)*K2 + h*hlen + ks*32 + kg*8);
        bf16x8 b0 = *(const bf16x8*)(lsb + n*NP + ks*32 + kg*8);
        bf16x8 b1 = *(const bf16x8*)(lsb + (16+n)*NP + ks*32 + kg*8);
        acc0 = __builtin_amdgcn_mfma_f32_16x16x32_bf16(af, b0, acc0, 0, 0, 0);
        acc1 = __builtin_amdgcn_mfma_f32_16x16x32_bf16(af, b1, acc1, 0, 0, 0);
    }
    #pragma unroll
    for (int r = 0; r < 4; ++r) {
        int row = w*16 + kg*4 + r;
        int j = row >> 1, comp = row & 1;
        size_t base = (((size_t)(pbase + c))*32 + j)*32;
        CO[(base + n)*2 + comp]      = acc0[r];
        CO[(base + 16 + n)*2 + comp] = acc1[r];
    }
}

// ---------------- spectral mix: float4, 8-way q-split, 4 modes/thread ----------------
__global__ __launch_bounds__(256) void k_spectral(
        const float* __restrict__ Wre, const float* __restrict__ Wim,
        const float* __restrict__ CINa, const float* __restrict__ CINb,
        float2* __restrict__ PART) {
    int part = blockIdx.y;
    int t = blockIdx.x * 256 + threadIdx.x;
    int p = t >> 8;
    int m4 = (t & 255) << 2;
    int q0 = part * 12;
    const float4* wr = (const float4*)(Wre + ((size_t)p * PP + q0) * 1024 + m4);
    const float4* wi = (const float4*)(Wim + ((size_t)p * PP + q0) * 1024 + m4);
    const float4* ca = (const float4*)(CINa + (size_t)q0 * 2048 + m4*2);
    const float4* cb = (const float4*)(CINb + (size_t)q0 * 2048 + m4*2);
    float re0=0,re1=0,re2=0,re3=0, im0=0,im1=0,im2=0,im3=0;
    #pragma unroll
    for (int q = 0; q < 12; ++q) {
        float4 a = wr[q * 256];
        float4 b = wi[q * 256];
        float4 c0 = ca[q * 512];
        float4 c1 = ca[q * 512 + 1];
        float4 d0 = cb[q * 512];
        float4 d1 = cb[q * 512 + 1];
        float cr0 = c0.x + d0.x, ci0 = c0.y + d0.y;
        float cr1 = c0.z + d0.z, ci1 = c0.w + d0.w;
        float cr2 = c1.x + d1.x, ci2 = c1.y + d1.y;
        float cr3 = c1.z + d1.z, ci3 = c1.w + d1.w;
        re0 += a.x*cr0 - b.x*ci0;  im0 += a.x*ci0 + b.x*cr0;
        re1 += a.y*cr1 - b.y*ci1;  im1 += a.y*ci1 + b.y*cr1;
        re2 += a.z*cr2 - b.z*ci2;  im2 += a.z*ci2 + b.z*cr2;
        re3 += a.w*cr3 - b.w*ci3;  im3 += a.w*ci3 + b.w*cr3;
    }
    float2* po = PART + ((size_t)part * PP + p) * 1024 + m4;
    po[0] = make_float2(re0, im0);
    po[1] = make_float2(re1, im1);
    po[2] = make_float2(re2, im2);
    po[3] = make_float2(re3, im3);
}

// ---------------- inverse DFT along y via MFMA (fuses 8-partial sum) ----------------
__global__ __launch_bounds__(256) void k_invy(
        const float2* __restrict__ PART,
        const short* __restrict__ TyIA, const short* __restrict__ TyIB,
        short* __restrict__ DA, short* __restrict__ DB) {
    __shared__ short A2[64*72];
    int bid = blockIdx.x;
    int c, yh, cb; const short* Ty; short* D;
    if (bid < 96) { c = bid >> 1; yh = bid & 1; Ty = TyIA; D = DA; cb = c; }
    else { c = bid - 96 + 48; yh = 0; Ty = TyIB; D = DB; cb = c - 48; }
    for (int idx = threadIdx.x; idx < 1024; idx += 256) {
        int j = idx >> 5, kx = idx & 31;
        float re = 0.f, im = 0.f;
        const float2* pp = PART + (size_t)c*1024 + idx;
        #pragma unroll
        for (int u = 0; u < 8; ++u) {
            float2 v = pp[(size_t)u*PP*1024];
            re += v.x; im += v.y;
        }
        A2[(2*kx+0)*72 + 2*j]   = f2bf(re);
        A2[(2*kx+0)*72 + 2*j+1] = f2bf(-im);
        A2[(2*kx+1)*72 + 2*j]   = f2bf(im);
        A2[(2*kx+1)*72 + 2*j+1] = f2bf(re);
    }
    __syncthreads();
    int wv = threadIdx.x >> 6, lane = threadIdx.x & 63;
    int n = lane & 15, kg = lane >> 4;
    #pragma unroll
    for (int ntl = 0; ntl < 2; ++ntl) {
        int nt = wv*2 + ntl;
        int y = yh*128 + nt*16 + n;
        bf16x8 bf0 = *(const bf16x8*)(Ty + (size_t)y*64 + kg*8);
        bf16x8 bf1 = *(const bf16x8*)(Ty + (size_t)y*64 + 32 + kg*8);
        #pragma unroll
        for (int mt = 0; mt < 4; ++mt) {
            bf16x8 a0 = *(const bf16x8*)(A2 + (mt*16 + n)*72 + kg*8);
            bf16x8 a1 = *(const bf16x8*)(A2 + (mt*16 + n)*72 + 32 + kg*8);
            f32x4 acc = {0.f,0.f,0.f,0.f};
            acc = __builtin_amdgcn_mfma_f32_16x16x32_bf16(a0, bf0, acc, 0, 0, 0);
            acc = __builtin_amdgcn_mfma_f32_16x16x32_bf16(a1, bf1, acc, 0, 0, 0);
            int row0 = mt*16 + kg*4;
            *(uint2*)(D + (size_t)y*3072 + cb*64 + row0) =
                make_uint2(pack2(acc[0], acc[1]), pack2(acc[2], acc[3]));
        }
    }
}

// ---------------- fused inverse tail ----------------
__global__ __launch_bounds__(256) void k_inv(
        const short* __restrict__ DA, const short* __restrict__ DB,
        float* __restrict__ UA, short* __restrict__ SBbf,
        const short* __restrict__ T2x, const short* __restrict__ T2xB,
        const short* __restrict__ W1T, const short* __restrict__ W2T,
        const float* __restrict__ b1v, const float* __restrict__ b2v) {
    __shared__ __attribute__((aligned(16))) char smc[37888];
    int t = threadIdx.x;
    int wv = t >> 6, lane = t & 63;
    int n = lane & 15, kg = lane >> 4;
    if (blockIdx.x < 512) {
        short* b0bf  = (short*)smc;                  // [128][72]
        short* slbf  = (short*)(smc + 18432);        // [128][72]
        float* bl1   = (float*)(smc + 37120);
        float* bl2   = (float*)(smc + 37312);
        int y  = blockIdx.x >> 1;
        int xh = (blockIdx.x & 1) << 7;
        if (t >= 64 && t < 112) bl1[t-64] = b1v[t-64];
        if (t >= 128 && t < 176) bl2[t-128] = b2v[t-128];
        const short* DAy = DA + (size_t)y*3072;
        {
            f32x4 acc[2][3];
            #pragma unroll
            for (int i = 0; i < 2; ++i)
                #pragma unroll
                for (int mt = 0; mt < 3; ++mt)
                    acc[i][mt] = (f32x4){0.f,0.f,0.f,0.f};
            #pragma unroll
            for (int ks = 0; ks < 2; ++ks) {
                bf16x8 bfr[2];
                #pragma unroll
                for (int i = 0; i < 2; ++i) {
                    int px = xh + (wv*2 + i)*16 + n;
                    bfr[i] = *(const bf16x8*)(T2x + (size_t)px*64 + ks*32 + kg*8);
                }
                #pragma unroll
                for (int mt = 0; mt < 3; ++mt) {
                    bf16x8 af = *(const bf16x8*)(DAy + (mt*16 + n)*64 + ks*32 + kg*8);
                    #pragma unroll
                    for (int i = 0; i < 2; ++i)
                        acc[i][mt] = __builtin_amdgcn_mfma_f32_16x16x32_bf16(af, bfr[i], acc[i][mt], 0, 0, 0);
                }
            }
            #pragma unroll
            for (int i = 0; i < 2; ++i) {
                int xl = (wv*2 + i)*16 + n;
                #pragma unroll
                for (int mt = 0; mt < 3; ++mt)
                    #pragma unroll
                    for (int r = 0; r < 4; ++r)
                        slbf[xl*72 + mt*16 + kg*4 + r] = f2bf(acc[i][mt][r]);
            }
            for (int idx = t; idx < 2048; idx += 256)
                slbf[(idx >> 4)*72 + 48 + (idx & 15)] = 0;
        }
        __syncthreads();
        {
            bf16x8 aw[3][2];
            #pragma unroll
            for (int mt = 0; mt < 3; ++mt)
                #pragma unroll
                for (int ks = 0; ks < 2; ++ks)
                    aw[mt][ks] = *(const bf16x8*)(W1T + (size_t)(mt*16 + n)*64 + ks*32 + kg*8);
            f32x4 acc[2][3];
            #pragma unroll
            for (int nt = 0; nt < 2; ++nt)
                #pragma unroll
                for (int mt = 0; mt < 3; ++mt)
                    acc[nt][mt] = (f32x4){0.f,0.f,0.f,0.f};
            #pragma unroll
            for (int nt = 0; nt < 2; ++nt) {
                int ntile = wv*2 + nt;
                #pragma unroll
                for (int ks = 0; ks < 2; ++ks) {
                    bf16x8 bfrag = *(const bf16x8*)(slbf + (size_t)(ntile*16 + n)*72 + ks*32 + kg*8);
                    #pragma unroll
                    for (int mt = 0; mt < 3; ++mt)
                        acc[nt][mt] = __builtin_amdgcn_mfma_f32_16x16x32_bf16(aw[mt][ks], bfrag, acc[nt][mt], 0, 0, 0);
                }
            }
            #pragma unroll
            for (int nt = 0; nt < 2; ++nt) {
                int px = (wv*2 + nt)*16 + n;
                #pragma unroll
                for (int mt = 0; mt < 3; ++mt) {
                    int oc0 = mt*16 + kg*4;
                    float g0 = gelu_f(acc[nt][mt][0] + bl1[oc0+0]);
                    float g1 = gelu_f(acc[nt][mt][1] + bl1[oc0+1]);
                    float g2 = gelu_f(acc[nt][mt][2] + bl1[oc0+2]);
                    float g3 = gelu_f(acc[nt][mt][3] + bl1[oc0+3]);
                    *(uint2*)(b0bf + (size_t)px*72 + oc0) = make_uint2(pack2(g0,g1), pack2(g2,g3));
                }
            }
            for (int idx = t; idx < 2048; idx += 256)
                b0bf[(idx >> 4)*72 + 48 + (idx & 15)] = 0;
        }
        __syncthreads();
        {
            bf16x8 aw[3][2];
            #pragma unroll
            for (int mt = 0; mt < 3; ++mt)
                #pragma unroll
                for (int ks = 0; ks < 2; ++ks)
                    aw[mt][ks] = *(const bf16x8*)(W2T + (size_t)(mt*16 + n)*64 + ks*32 + kg*8);
            f32x4 acc[2][3];
            #pragma unroll
            for (int nt = 0; nt < 2; ++nt)
                #pragma unroll
                for (int mt = 0; mt < 3; ++mt)
                    acc[nt][mt] = (f32x4){0.f,0.f,0.f,0.f};
            #pragma unroll
            for (int nt = 0; nt < 2; ++nt) {
                int ntile = wv*2 + nt;
                #pragma unroll
                for (int ks = 0; ks < 2; ++ks) {
                    bf16x8 bfrag = *(const bf16x8*)(b0bf + (size_t)(ntile*16 + n)*72 + ks*32 + kg*8);
                    #pragma unroll
                    for (int mt = 0; mt < 3; ++mt)
                        acc[nt][mt] = __builtin_amdgcn_mfma_f32_16x16x32_bf16(aw[mt][ks], bfrag, acc[nt][mt], 0, 0, 0);
                }
            }
            #pragma unroll
            for (int nt = 0; nt < 2; ++nt) {
                int px = (wv*2 + nt)*16 + n;
                #pragma unroll
                for (int mt = 0; mt < 3; ++mt) {
                    int oc0 = mt*16 + kg*4;
                    #pragma unroll
                    for (int r = 0; r < 4; ++r) {
                        int oc = oc0 + r;
                        size_t o = (size_t)oc*NPIXA + (size_t)y*WA + xh + px;
                        UA[o] = gelu_f(acc[nt][mt][r] + bl2[oc]) + UA[o];
                    }
                }
            }
        }
    } else {
        int y = blockIdx.x - 512;
        short* sbuf = (short*)smc;    // [48][132]
        const short* DBy = DB + (size_t)y*3072;
        #pragma unroll
        for (int ntl = 0; ntl < 2; ++ntl) {
            int nt = wv*2 + ntl;
            int x = nt*16 + n;
            bf16x8 bf0 = *(const bf16x8*)(T2xB + (size_t)x*64 + kg*8);
            bf16x8 bf1 = *(const bf16x8*)(T2xB + (size_t)x*64 + 32 + kg*8);
            #pragma unroll
            for (int mt = 0; mt < 3; ++mt) {
                bf16x8 a0 = *(const bf16x8*)(DBy + (mt*16 + n)*64 + kg*8);
                bf16x8 a1 = *(const bf16x8*)(DBy + (mt*16 + n)*64 + 32 + kg*8);
                f32x4 acc = {0.f,0.f,0.f,0.f};
                acc = __builtin_amdgcn_mfma_f32_16x16x32_bf16(a0, bf0, acc, 0, 0, 0);
                acc = __builtin_amdgcn_mfma_f32_16x16x32_bf16(a1, bf1, acc, 0, 0, 0);
                int c0 = mt*16 + kg*4;
                #pragma unroll
                for (int r = 0; r < 4; ++r)
                    sbuf[(c0 + r)*132 + x] = f2bf(acc[r]);
            }
        }
        __syncthreads();
        for (int idx = t; idx < 3072; idx += 256) {
            int x = idx / 24, cu = idx - x*24;
            unsigned v = (unsigned)(unsigned short)sbuf[(2*cu)*132 + x]
                       | ((unsigned)(unsigned short)sbuf[(2*cu+1)*132 + x] << 16);
            *(unsigned*)(SBbf + ((size_t)y*WB + x)*48 + 2*cu) = v;
        }
    }
}

// ---------------- B-branch 3x3 conv via MFMA, pixel-major bf16 I/O ----------------
// block = 384 threads (6 waves = 2nt x 3mt), 1 row x 32 px x 48 oc. grid 512.
__global__ __launch_bounds__(384) void k_conv3x3_mfma(
        const short* __restrict__ in, float* __restrict__ outf,
        short* __restrict__ outbf,
        const short* __restrict__ wt, const float* __restrict__ bias,
        const float* resid) {
    __shared__ __attribute__((aligned(16))) short tile[3*34*72];   // 14688 B
    int y  = blockIdx.x >> 2;
    int x0 = (blockIdx.x & 3) << 5;
    int tid = threadIdx.x;
    for (int idx = tid; idx < 102*6; idx += 384) {
        int pix = idx / 6, chunk = idx - pix*6;
        int r = pix / 34, px = pix - r*34;
        int gy = y - 1 + r, gx = x0 - 1 + px;
        uint4 v = {0u,0u,0u,0u};
        if (gy >= 0 && gy < HB && gx >= 0 && gx < WB)
            v = *(const uint4*)(in + ((size_t)gy*WB + gx)*48 + chunk*8);
        *(uint4*)(tile + pix*72 + chunk*8) = v;
    }
    for (int idx = tid; idx < 102*2; idx += 384) {
        int pix = idx >> 1, h = idx & 1;
        *(uint4*)(tile + pix*72 + 48 + h*8) = (uint4){0u,0u,0u,0u};
    }
    __syncthreads();

    int wv = tid / 64, lane = tid & 63;
    int n = lane & 15, kg = lane >> 4;
    int nt = wv & 1, mt = wv >> 1;   // nt 0..1, mt 0..2
    f32x4 acc = {0.f,0.f,0.f,0.f};
    #pragma unroll
    for (int tap = 0; tap < 9; ++tap) {
        int dy = tap / 3, dx = tap - dy*3;
        int pxl = nt*16 + n + dx;
        const short* brow = tile + (dy*34 + pxl)*72;
        const short* ap = wt + (size_t)tap*3072 + (size_t)(mt*16 + n)*64;
        #pragma unroll
        for (int ks = 0; ks < 2; ++ks) {
            bf16x8 bfrag = *(const bf16x8*)(brow + ks*32 + kg*8);
            bf16x8 afrag = *(const bf16x8*)(ap + ks*32 + kg*8);
            acc = __builtin_amdgcn_mfma_f32_16x16x32_bf16(afrag, bfrag, acc, 0, 0, 0);
        }
    }
    int px_g = x0 + nt*16 + n;
    int oc0 = mt*16 + kg*4;
    float g0 = gelu_f(acc[0] + bias[oc0+0]);
    float g1 = gelu_f(acc[1] + bias[oc0+1]);
    float g2 = gelu_f(acc[2] + bias[oc0+2]);
    float g3 = gelu_f(acc[3] + bias[oc0+3]);
    if (outbf) {
        *(uint2*)(outbf + ((size_t)y*WB + px_g)*48 + oc0) =
            make_uint2(pack2(g0, g1), pack2(g2, g3));
    } else {
        float gv[4] = {g0, g1, g2, g3};
        #pragma unroll
        for (int r = 0; r < 4; ++r) {
            size_t o = (size_t)(oc0 + r)*NPIXB + (size_t)y*WB + px_g;
            outf[o] = gv[r] + resid[o];
        }
    }
}

// ---------------- decoder ----------------
__global__ __launch_bounds__(256) void k_decode(
        const float* __restrict__ UA, const float* __restrict__ UB,
        const float* dwa, const float* dba,
        const float* dwb, const float* dbb, float* outp) {
    int t = blockIdx.x*256 + threadIdx.x;
    if (t < NPIXA) {
        float acc = dba[0];
        #pragma unroll 8
        for (int p = 0; p < PA; ++p) acc += dwa[p]*UA[(size_t)p*NPIXA + t];
        outp[t] = acc;
    } else {
        int u = t - NPIXA;
        float acc = dbb[0];
        #pragma unroll 8
        for (int p = 0; p < PB; ++p) acc += dwb[p]*UB[(size_t)p*NPIXB + u];
        outp[t] = acc;
    }
}

extern "C" void kernel_launch(void* const* d_in, const int* in_sizes, int n_in,
                              void* d_out, int out_size, void* d_ws, size_t ws_size,
                              hipStream_t stream) {
    const float* u_a   = (const float*)d_in[0];
    const float* x_a   = (const float*)d_in[1];
    const float* u_b   = (const float*)d_in[2];
    const float* x_b   = (const float*)d_in[3];
    const float* enc_a_w = (const float*)d_in[4];
    const float* enc_a_b = (const float*)d_in[5];
    const float* enc_b_w = (const float*)d_in[6];
    const float* enc_b_b = (const float*)d_in[7];
    const float* dec_a_w = (const float*)d_in[8];
    const float* dec_a_b = (const float*)d_in[9];
    const float* dec_b_w = (const float*)d_in[10];
    const float* dec_b_b = (const float*)d_in[11];
    const float* c1a_w = (const float*)d_in[12];
    const float* c1a_b = (const float*)d_in[13];
    const float* c2a_w = (const float*)d_in[14];
    const float* c2a_b = (const float*)d_in[15];
    const float* c1b_w = (const float*)d_in[16];
    const float* c1b_b = (const float*)d_in[17];
    const float* c2b_w = (const float*)d_in[18];
    const float* c2b_b = (const float*)d_in[19];
    const float* A_re = (const float*)d_in[20];
    const float* A_im = (const float*)d_in[21];

    float* ws = (float*)d_ws;
    size_t off = 0;
    auto alloc = [&](size_t n) { float* p = ws + off; off += n; return p; };
    short* WT    = (short*)alloc(4*2*9*48*64/2);
    short* TbfA  = (short*)alloc(64*WA/2);
    short* TbfB  = (short*)alloc(64*WB/2);
    short* WcT   = (short*)alloc(4*2*48*64/2);
    short* T2x   = (short*)alloc(WA*64/2);
    short* T2xB  = (short*)alloc(WB*64/2);
    short* Ty2A  = (short*)alloc(64*512/2);
    short* Ty2B  = (short*)alloc(64*256/2);
    short* TyIA  = (short*)alloc(HA*64/2);
    short* TyIB  = (short*)alloc(HB*64/2);
    float* TiyA  = alloc(MM*HA*2);
    float* TixB  = alloc(MM*WB*2);
    float* TiyB  = alloc(MM*HB*2);
    float* UA = alloc((size_t)PA*NPIXA);
    float* UB = alloc((size_t)PB*NPIXB);
    short* SBbf = (short*)alloc((size_t)PB*NPIXB/2);
    short* TBbf = (short*)alloc((size_t)PB*NPIXB/2);
    short* FTA = (short*)alloc((size_t)PA*MM*512/2);
    short* FTB = (short*)alloc((size_t)PB*MM*256/2);
    short* DA  = (short*)alloc((size_t)HA*3072/2);
    short* DB  = (short*)alloc((size_t)HB*3072/2);
    float* CINa = alloc((size_t)PP*MM*MM*2);
    float* CINb = alloc((size_t)PP*MM*MM*2);
    float2* PART = (float2*)alloc((size_t)8*PP*MM*MM*2);
    if (off * sizeof(float) > ws_size) return;

    k_pre<<<dim3(16784), dim3(256), 0, stream>>>(
        TiyA, TixB, TiyB, T2x,
        u_a,x_a,u_b,x_b, enc_a_w,enc_a_b,enc_b_w,enc_b_b, UA,UB,
        c1b_w, c2b_w, WT, TbfA, TbfB, c1a_w, c2a_w, WcT, Ty2A, Ty2B,
        TyIA, TyIB, T2xB);
    for (int l = 0; l < 4; ++l) {
        k_fwd_x<<<dim3(576), dim3(256), 32*(WA+8)*2, stream>>>(UA,UB,FTA,FTB,TbfA,TbfB);
        k_fwd_y<<<dim3(192), dim3(256), 0, stream>>>(FTA,FTB,Ty2A,Ty2B,CINa,CINb);
        k_spectral<<<dim3(96,8), dim3(256), 0, stream>>>(
            A_re + (size_t)l*PP*PP*MM*MM, A_im + (size_t)l*PP*PP*MM*MM,
            CINa, CINb, PART);
        k_invy<<<dim3(144), dim3(256), 0, stream>>>(PART, TyIA, TyIB, DA, DB);
        k_inv<<<dim3(512 + 128), dim3(256), 0, stream>>>(DA, DB, UA, SBbf,
            T2x, T2xB,
            WcT + (size_t)(l*2 + 0)*3072, WcT + (size_t)(l*2 + 1)*3072,
            c1a_b + (size_t)l*PA, c2a_b + (size_t)l*PA);
        k_conv3x3_mfma<<<dim3(512), dim3(384), 0, stream>>>(SBbf, (float*)nullptr, TBbf,
            WT + (size_t)(l*2 + 0)*27648, c1b_b + (size_t)l*PB, (const float*)nullptr);
        k_conv3x3_mfma<<<dim3(512), dim3(384), 0, stream>>>(TBbf, UB, (short*)nullptr,
            WT + (size_t)(l*2 + 1)*27648, c2b_b + (size_t)l*PB, UB);
    }
    k_decode<<<dim3(320), dim3(256), 0, stream>>>(UA, UB,
        dec_a_w, dec_a_b, dec_b_w, dec_b_b, (float*)d_out);
}